// Round 10
// baseline (376.391 us; speedup 1.0000x reference)
//
#include <hip/hip_runtime.h>
#include <math.h>

#define HID 32
#define HOR 12
#define NB  256   // first-level blocks; k_binscan's 256 threads own one block each
#define GSH 8     // group shift: 256 nodes per group (392 write streams in scatter)
#define GW  256   // group width
#define NPT 4     // nodes per thread in k_gates general path

__device__ __forceinline__ float sigmoidf_(float x) { return 1.0f / (1.0f + expf(-x)); }

// ---------------------------------------------------------------------------
// Pipeline identical to round 9 except k_gates fast path, redesigned as:
//   wave = output-feature octet (j0 = wave_id*8), lane = node.
// Weight addresses are wave-uniform -> scalar s_load (zero vector cost);
// inputs live per-lane in registers; k-loop has NO cross-lane ops.
// Head uses a transposed LDS H tile (both sides conflict-free).
// ---------------------------------------------------------------------------

__global__ __launch_bounds__(1024) void k_hist(const int* __restrict__ src,
                                               const int* __restrict__ dst,
                                               int* __restrict__ hist,
                                               int E, int chunk, int ng) {
    __shared__ int hS[GW], hD[GW];
    int t = threadIdx.x, b = blockIdx.x;
    for (int i = t; i < ng; i += 1024) { hS[i] = 0; hD[i] = 0; }
    __syncthreads();
    int beg = b * chunk, end = min(E, beg + chunk);
    for (int e = beg + t; e < end; e += 1024) {
        atomicAdd(&hS[src[e] >> GSH], 1);
        atomicAdd(&hD[dst[e] >> GSH], 1);
    }
    __syncthreads();
    for (int i = t; i < ng; i += 1024) {
        hist[(size_t)i * NB + b] = hS[i];               // S bins: [0, ng)
        hist[((size_t)ng + i) * NB + b] = hD[i];        // D bins: [ng, 2ng)
    }
}

// per-bin exclusive scan across the NB blocks (one block per bin)
__global__ __launch_bounds__(256) void k_binscan(const int* __restrict__ hist,
                                                 int* __restrict__ off,
                                                 int* __restrict__ binTot, int ng2) {
    __shared__ int s[256];
    int b2 = blockIdx.x, t = threadIdx.x;
    int v = hist[(size_t)b2 * NB + t];                  // coalesced
    s[t] = v;
    __syncthreads();
    for (int o = 1; o < 256; o <<= 1) {
        int x = (t >= o) ? s[t - o] : 0;
        __syncthreads();
        s[t] += x;
        __syncthreads();
    }
    off[(size_t)t * ng2 + b2] = s[t] - v;               // block-major (scattered)
    if (t == 255) binTot[b2] = s[255];
}

// 2 blocks x 1024: block 0 scans S bin totals, block 1 scans D bin totals.
__global__ __launch_bounds__(1024) void k_binbase(const int* __restrict__ binTot,
                                                  int* __restrict__ baseS, int* __restrict__ baseD,
                                                  int* __restrict__ rowptr,
                                                  int E, int ng, int N) {
    __shared__ int buf[1024];
    int t = threadIdx.x;
    int isD = blockIdx.x;
    int sum = (t < ng) ? binTot[isD * ng + t] : 0;
    buf[t] = sum;
    __syncthreads();
    for (int o = 1; o < 1024; o <<= 1) {
        int v = (t >= o) ? buf[t - o] : 0;
        __syncthreads();
        buf[t] += v;
        __syncthreads();
    }
    int base = buf[t] - sum;                            // exclusive
    int* B = isD ? baseD : baseS;
    if (t < ng) B[t] = base;
    if (t == 0) { B[ng] = E; if (!isD) rowptr[N] = E; }
}

// per-edge scatter into 256-wide groups (both keyings) using LDS cursors.
__global__ __launch_bounds__(1024) void k_scatter(const int* __restrict__ src,
                                                  const int* __restrict__ dst,
                                                  const float* __restrict__ w,
                                                  const int* __restrict__ off,
                                                  const int* __restrict__ baseS,
                                                  const int* __restrict__ baseD,
                                                  int2* __restrict__ tmpS, int2* __restrict__ tmpD,
                                                  int E, int chunk, int ng) {
    __shared__ int cS[GW], cD[GW];
    int t = threadIdx.x, b = blockIdx.x;
    int ng2 = 2 * ng;
    for (int i = t; i < ng; i += 1024) {
        cS[i] = off[(size_t)b * ng2 + i] + baseS[i];          // coalesced
        cD[i] = off[(size_t)b * ng2 + ng + i] + baseD[i];
    }
    __syncthreads();
    int beg = b * chunk, end = min(E, beg + chunk);
    for (int e = beg + t; e < end; e += 1024) {
        int s = src[e], d = dst[e];
        int wb = __float_as_int(w[e]);
        int pS = atomicAdd(&cS[s >> GSH], 1);
        tmpS[pS] = make_int2(s, wb);
        int pD = atomicAdd(&cD[d >> GSH], 1);
        tmpD[pD] = make_int2(s | ((d & (GW - 1)) << 16), wb); // src fits 16 bits
    }
}

// per src-group: LDS float histogram over low 8 bits -> dinv (no global atomics)
__global__ __launch_bounds__(256) void k_degsum(const int2* __restrict__ tmpS,
                                                const int* __restrict__ baseS,
                                                float* __restrict__ dinv, int N) {
    __shared__ float h[GW];
    int g = blockIdx.x, t = threadIdx.x;
    h[t] = 0.0f;
    __syncthreads();
    int beg = baseS[g], end = baseS[g + 1];
    for (int i = beg + t; i < end; i += 256) {
        int2 p = tmpS[i];
        atomicAdd(&h[p.x & (GW - 1)], __int_as_float(p.y));
    }
    __syncthreads();
    int n = (g << GSH) + t;
    if (n < N) { float s = h[t]; dinv[n] = (s > 0.0f) ? rsqrtf(s) : 0.0f; }
}

// per dst-group: low-bits count + scan -> rowptr; then bin edges to exact dst,
// computing nw now that dinv exists. Within-dst order is arbitrary (sum).
__global__ __launch_bounds__(256) void k_scatter2(const int2* __restrict__ tmpD,
                                                  const int* __restrict__ baseD,
                                                  const float* __restrict__ dinv,
                                                  int* __restrict__ rowptr,
                                                  int2* __restrict__ epair, int N) {
    __shared__ int h[GW], cur[GW];
    int g = blockIdx.x, t = threadIdx.x;
    h[t] = 0;
    __syncthreads();
    int beg = baseD[g], end = baseD[g + 1];
    for (int i = beg + t; i < end; i += 256) atomicAdd(&h[(tmpD[i].x >> 16) & (GW - 1)], 1);
    __syncthreads();
    int v = h[t];
    for (int o = 1; o < GW; o <<= 1) {
        int x = (t >= o) ? h[t - o] : 0;
        __syncthreads();
        h[t] += x;
        __syncthreads();
    }
    int excl = h[t] - v;
    int n = (g << GSH) + t;
    if (n < N) rowptr[n] = beg + excl;
    cur[t] = beg + excl;
    __syncthreads();
    for (int i = beg + t; i < end; i += 256) {
        int2 p = tmpD[i];
        int low = (p.x >> 16) & (GW - 1);
        int s = p.x & 0xFFFF;
        int pos = atomicAdd(&cur[low], 1);
        float nw = -dinv[s] * __int_as_float(p.y) * dinv[(g << GSH) + low];
        epair[pos] = make_int2(s, __float_as_int(nw));
    }
}

// flag bit0 = any h0 nonzero, bit1 = any c0 nonzero
__global__ void k_flags(const float* __restrict__ h0, const float* __restrict__ c0,
                        int* __restrict__ flag, int total) {
    int i = blockIdx.x * 256 + threadIdx.x;
    float a = (i < total) ? h0[i] : 0.0f;
    float c = (i < total) ? c0[i] : 0.0f;
    unsigned long long ba = __ballot(a != 0.0f);
    unsigned long long bc = __ballot(c != 0.0f);
    if ((threadIdx.x & 63) == 0) {
        int m = (ba ? 1 : 0) | (bc ? 2 : 0);
        if (m) atomicOr(flag, m);
    }
}

// per dst node (32 lanes = 32 feats): accumulate LX (and LH if h0 nonzero)
__global__ __launch_bounds__(256) void k_gather(const int* __restrict__ rowptr,
                                                const int2* __restrict__ epair,
                                                const float* __restrict__ X,
                                                const float* __restrict__ H0,
                                                const int* __restrict__ hflag,
                                                float* __restrict__ LX, float* __restrict__ LH,
                                                int N) {
    int tid = blockIdx.x * 256 + threadIdx.x;
    int n = tid >> 5;
    int f = tid & 31;
    if (n >= N) return;
    int beg = rowptr[n], end = rowptr[n + 1];
    float acc = 0.0f, accH = 0.0f;
    int fl = *hflag;
    if (fl & 1) {
        #pragma unroll 4
        for (int i = beg; i < end; ++i) {
            int2 p = epair[i];
            float w = __int_as_float(p.y);
            acc  += w * X[(p.x << 5) + f];
            accH += w * H0[(p.x << 5) + f];
        }
    } else {
        #pragma unroll 4
        for (int i = beg; i < end; ++i) {
            int2 p = epair[i];
            acc += __int_as_float(p.y) * X[(p.x << 5) + f];
        }
    }
    LX[(n << 5) + f] = acc;
    if (fl & 1) LH[(n << 5) + f] = accH;   // LH is logically 0 otherwise; never read then
}

// Fast path: wave = feature octet, lane = node; scalar-pipe weights.
// General path: proven round-8 shfl form (correctness-only; never hot here).
__global__ __launch_bounds__(256) void k_gates(
    const float* __restrict__ X, const float* __restrict__ LX,
    const float* __restrict__ H0, const float* __restrict__ LH,
    const float* __restrict__ C0,
    const float* __restrict__ Wx, const float* __restrict__ bx,
    const float* __restrict__ Wh, const float* __restrict__ bh,
    const float* __restrict__ wc, const float* __restrict__ b,
    const float* __restrict__ Wl, const float* __restrict__ bl,
    const int* __restrict__ flag,
    float* __restrict__ hOut, float* __restrict__ outH, float* __restrict__ outC,
    int N) {
    __shared__ float Hl[HID][64];   // transposed relu(H) tile, 8 KB
    int f2 = *flag;

    if (f2 == 0) {
        // ---- fast path: h0 == 0 and c0 == 0 ----
        int fastB = (N + 63) >> 6;
        if (blockIdx.x >= fastB) return;
        int t = threadIdx.x;
        int ln = t & 63;                                   // node within block
        int n = (blockIdx.x << 6) + ln;
        int jc = __builtin_amdgcn_readfirstlane(t >> 6);   // wave id 0..3 (uniform)
        int j0 = jc << 3;                                  // feature octet base

        if (n < N) {
            // per-lane input rows in registers (static-indexed -> VGPRs)
            const float4* Xr = (const float4*)(X + ((size_t)n << 5));
            const float4* Lr = (const float4*)(LX + ((size_t)n << 5));
            float4 x4[8], l4[8];
            #pragma unroll
            for (int q = 0; q < 8; ++q) { x4[q] = Xr[q]; l4[q] = Lr[q]; }
            float xr[HID], lr[HID];
            #pragma unroll
            for (int q = 0; q < 8; ++q) {
                xr[4*q+0] = x4[q].x; xr[4*q+1] = x4[q].y; xr[4*q+2] = x4[q].z; xr[4*q+3] = x4[q].w;
                lr[4*q+0] = l4[q].x; lr[4*q+1] = l4[q].y; lr[4*q+2] = l4[q].z; lr[4*q+3] = l4[q].w;
            }

            // accumulators: gates I (0), T (2), O (3), 8 features each
            float aI[8], aT[8], aO[8];
            #pragma unroll
            for (int jj = 0; jj < 8; ++jj) {
                aI[jj] = bx[j0 + jj]           + bh[j0 + jj]           + b[j0 + jj];
                aT[jj] = bx[2*HID + j0 + jj]   + bh[2*HID + j0 + jj]   + b[2*HID + j0 + jj];
                aO[jj] = bx[3*HID + j0 + jj]   + bh[3*HID + j0 + jj]   + b[3*HID + j0 + jj];
            }

            // wave-uniform weight bases -> scalar loads in the k-loop
            const float* W0x = Wx + j0;                // gate0, X half
            const float* W0l = Wx + 1024 + j0;         // gate0, LX half
            const float* W2x = Wx + 2*2048 + j0;
            const float* W2l = Wx + 2*2048 + 1024 + j0;
            const float* W3x = Wx + 3*2048 + j0;
            const float* W3l = Wx + 3*2048 + 1024 + j0;

            #pragma unroll
            for (int k = 0; k < HID; ++k) {
                float xv = xr[k], lv = lr[k];
                int r = k << 5;
                #pragma unroll
                for (int jj = 0; jj < 8; ++jj) {
                    aI[jj] += xv * W0x[r + jj] + lv * W0l[r + jj];
                    aT[jj] += xv * W2x[r + jj] + lv * W2l[r + jj];
                    aO[jj] += xv * W3x[r + jj] + lv * W3l[r + jj];
                }
            }

            float h8[8], c8[8];
            #pragma unroll
            for (int jj = 0; jj < 8; ++jj) {
                float I = sigmoidf_(aI[jj]);
                float T = tanhf(aT[jj]);
                float C = I * T;
                float O = sigmoidf_(aO[jj] + wc[2*HID + j0 + jj] * C);
                float H = O * tanhf(C);
                h8[jj] = H;
                c8[jj] = C;
                Hl[j0 + jj][ln] = fmaxf(H, 0.0f);      // transposed, conflict-free
            }
            size_t base = ((size_t)n << 5) + j0;
            *(float4*)(outH + base)     = make_float4(h8[0], h8[1], h8[2], h8[3]);
            *(float4*)(outH + base + 4) = make_float4(h8[4], h8[5], h8[6], h8[7]);
            *(float4*)(outC + base)     = make_float4(c8[0], c8[1], c8[2], c8[3]);
            *(float4*)(outC + base + 4) = make_float4(c8[4], c8[5], c8[6], c8[7]);
        }
        __syncthreads();

        // head: thread -> (node = t&63, 3 horizons); Wl loads wave-uniform
        int hn = t & 63;
        int hw = __builtin_amdgcn_readfirstlane(t >> 6);
        int n2 = (blockIdx.x << 6) + hn;
        if (n2 < N) {
            int jb = hw * 3;
            float a0 = bl[jb], a1 = bl[jb + 1], a2 = bl[jb + 2];
            #pragma unroll
            for (int k = 0; k < HID; ++k) {
                float hv = Hl[k][hn];                  // consecutive lanes, conflict-free
                a0 += hv * Wl[k * HOR + jb];
                a1 += hv * Wl[k * HOR + jb + 1];
                a2 += hv * Wl[k * HOR + jb + 2];
            }
            size_t ob = (size_t)n2 * HOR + jb;
            hOut[ob] = a0; hOut[ob + 1] = a1; hOut[ob + 2] = a2;
        }
        return;
    }

    // ---- general path (shfl form; correctness-only) ----
    int tid = blockIdx.x * 256 + threadIdx.x;
    int g = tid >> 5;
    int j = tid & 31;
    int n0 = g * NPT;
    if (n0 >= N) return;
    int cnt = min(NPT, N - n0);
    float blv = (j < HOR) ? bl[j] : 0.0f;

    float xk[NPT], lxk[NPT], hk[NPT], lhk[NPT];
    #pragma unroll
    for (int i = 0; i < NPT; ++i) { xk[i] = 0.0f; lxk[i] = 0.0f; hk[i] = 0.0f; lhk[i] = 0.0f; }
    for (int i = 0; i < cnt; ++i) {
        int base = (n0 + i) << 5;
        xk[i]  = X[base + j];
        lxk[i] = LX[base + j];
        hk[i]  = H0[base + j];
        lhk[i] = (f2 & 1) ? LH[base + j] : 0.0f;   // LH only valid if h0 nonzero
    }

    float pre[4][NPT];
    #pragma unroll
    for (int gt = 0; gt < 4; ++gt) {
        float bb = bx[gt * HID + j] + bh[gt * HID + j] + b[gt * HID + j];
        #pragma unroll
        for (int i = 0; i < NPT; ++i) pre[gt][i] = bb;
    }

    #pragma unroll 2
    for (int k = 0; k < HID; ++k) {
        float w0[4], w1[4], w2[4], w3[4];
        int row = k * HID + j;
        #pragma unroll
        for (int gt = 0; gt < 4; ++gt) {
            w0[gt] = Wx[gt * 2048 + row];
            w1[gt] = Wx[gt * 2048 + 1024 + row];
            w2[gt] = Wh[gt * 2048 + row];
            w3[gt] = Wh[gt * 2048 + 1024 + row];
        }
        #pragma unroll
        for (int i = 0; i < NPT; ++i) {
            float xv  = __shfl(xk[i],  k, 32);
            float lxv = __shfl(lxk[i], k, 32);
            float hv  = __shfl(hk[i],  k, 32);
            float lhv = __shfl(lhk[i], k, 32);
            #pragma unroll
            for (int gt = 0; gt < 4; ++gt)
                pre[gt][i] += xv * w0[gt] + lxv * w1[gt] + hv * w2[gt] + lhv * w3[gt];
        }
    }

    float wc0 = wc[0 * HID + j], wc1 = wc[1 * HID + j], wc2 = wc[2 * HID + j];
    for (int i = 0; i < cnt; ++i) {
        int n = n0 + i;
        int base = n << 5;
        float c0v = C0[base + j];
        float I  = sigmoidf_(pre[0][i] + wc0 * c0v);
        float Fg = sigmoidf_(pre[1][i] + wc1 * c0v);
        float T  = tanhf(pre[2][i]);
        float C  = Fg * c0v + I * T;
        float O  = sigmoidf_(pre[3][i] + wc2 * C);
        float H  = O * tanhf(C);
        outH[base + j] = H;
        outC[base + j] = C;
        float ah = blv;
        #pragma unroll 8
        for (int k = 0; k < HID; ++k) {
            float hv = __shfl(H, k, 32);
            if (j < HOR) ah += fmaxf(hv, 0.0f) * Wl[k * HOR + j];
        }
        if (j < HOR) hOut[(size_t)n * HOR + j] = ah;
    }
}

extern "C" void kernel_launch(void* const* d_in, const int* in_sizes, int n_in,
                              void* d_out, int out_size, void* d_ws, size_t ws_size,
                              hipStream_t stream) {
    const float* x  = (const float*)d_in[0];
    const int*   ei = (const int*)d_in[1];
    const float* ew = (const float*)d_in[2];
    const float* Wx = (const float*)d_in[3];
    const float* bx = (const float*)d_in[4];
    const float* Wh = (const float*)d_in[5];
    const float* bh = (const float*)d_in[6];
    const float* wc = (const float*)d_in[7];
    const float* b  = (const float*)d_in[8];
    const float* Wl = (const float*)d_in[9];
    const float* bl = (const float*)d_in[10];
    const float* h0 = (const float*)d_in[11];
    const float* c0 = (const float*)d_in[12];

    int N = in_sizes[0] / HID;      // x is (N,1,32)
    int E = in_sizes[2];            // edge_weight is (E,)
    const int* src = ei;
    const int* dst = ei + E;

    int ng = (N + GW - 1) >> GSH;   // 196 groups (requires N <= 65536)
    int ng2 = 2 * ng;
    int chunk = (E + NB - 1) / NB;  // edges per hist/scatter block

    // workspace (4-byte units):
    // [tmpD 2E] [tmpS 2E (aliased by epair)] [LX N*32] [LH N*32] [rowptr N+1]
    // [hist ng2*NB] [off ng2*NB] [binTot 2048] [baseS ng+1] [baseD ng+1] [dinv N] [flag 1]
    // tmpS is dead after k_degsum, so k_scatter2 may overwrite it with epair.
    int* wsi = (int*)d_ws;
    int2*  tmpD   = (int2*)wsi;
    int2*  tmpS   = (int2*)(wsi + 2 * (size_t)E);
    int2*  epair  = tmpS;                                // alias (see above)
    float* LX     = (float*)(wsi + 4 * (size_t)E);
    float* LH     = LX + (size_t)N * HID;
    int*   rowptr = (int*)(LH + (size_t)N * HID);
    int*   hist   = rowptr + (N + 1);
    int*   off    = hist + (size_t)ng2 * NB;
    int*   binTot = off + (size_t)ng2 * NB;
    int*   baseS  = binTot + 2048;
    int*   baseD  = baseS + (ng + 1);
    float* dinv   = (float*)(baseD + (ng + 1));
    int*   flag   = (int*)(dinv + N);

    float* hOut = (float*)d_out;            // (N,12)
    float* HOut = hOut + (size_t)N * HOR;   // (N,32)
    float* COut = HOut + (size_t)N * HID;   // (N,32)

    hipMemsetAsync(flag, 0, sizeof(int), stream);

    k_hist<<<NB, 1024, 0, stream>>>(src, dst, hist, E, chunk, ng);
    k_binscan<<<ng2, 256, 0, stream>>>(hist, off, binTot, ng2);
    k_binbase<<<2, 1024, 0, stream>>>(binTot, baseS, baseD, rowptr, E, ng, N);
    k_scatter<<<NB, 1024, 0, stream>>>(src, dst, ew, off, baseS, baseD, tmpS, tmpD, E, chunk, ng);
    k_degsum<<<ng, 256, 0, stream>>>(tmpS, baseS, dinv, N);
    k_flags<<<(N * HID + 255) / 256, 256, 0, stream>>>(h0, c0, flag, N * HID);
    k_scatter2<<<ng, 256, 0, stream>>>(tmpD, baseD, dinv, rowptr, epair, N);

    k_gather<<<(N * HID + 255) / 256, 256, 0, stream>>>(rowptr, epair, x, h0, flag, LX, LH, N);

    int gThreads = ((N + NPT - 1) / NPT) * 32;
    k_gates<<<(gThreads + 255) / 256, 256, 0, stream>>>(x, LX, h0, LH, c0,
                                                        Wx, bx, Wh, bh, wc, b, Wl, bl, flag,
                                                        hOut, HOut, COut, N);
}